// Round 8
// baseline (175.977 us; speedup 1.0000x reference)
//
#include <hip/hip_runtime.h>
#include <hip/hip_bf16.h>
#include <cstdint>
#include <cstddef>

#define NB   8
#define CIN  128
#define COUT 64
#define NPIX 131072
#define PLANE NPIX
#define LOG2E 1.44269504088896340736f

typedef _Float16 f16;
typedef _Float16 half4_t __attribute__((ext_vector_type(4)));
typedef _Float16 half8_t __attribute__((ext_vector_type(8)));
typedef float    float4_t __attribute__((ext_vector_type(4)));

// ============ Kernel 1: 1x1 convs, W-stationary MFMA (W converted in-reg) ============
__global__ __launch_bounds__(256, 4) void conv_mfma_k(
    const float* __restrict__ x,  const float* __restrict__ W1,
    const float* __restrict__ W2, const float* __restrict__ W3,
    f16* __restrict__ Qi, f16* __restrict__ Ki, f16* __restrict__ V2)
{
  __shared__ __align__(16) f16 xs[64 * 136];     // 17.4 KB

  int tid = threadIdx.x, lane = tid & 63, wv = tid >> 6;
  int b = blockIdx.x;
  int n = b & 7, t = b >> 3;                     // image n -> XCD n
  int pxt = (n << 14) + t * 64;
  int hwt = pxt & 16383;

  // stage x[c][px] fp32 -> LDS [px][c] f16 (wave wv: channel strip wv*32)
  {
    const float* xp = x + ((size_t)(n * CIN + wv * 32) << 14) + hwt + lane;
    #pragma unroll
    for (int c0 = 0; c0 < 32; c0 += 8) {
      half8_t hh;
      #pragma unroll
      for (int j = 0; j < 8; ++j)
        hh[j] = (f16)xp[(size_t)(c0 + j) << 14];
      *(half8_t*)&xs[lane * 136 + wv * 32 + c0] = hh;
    }
  }

  int l15 = lane & 15, q4 = lane >> 4;

  // W frags direct from fp32 global (rows = cout = wv*16 + l15); W1 pre-scaled by log2e
  half8_t wq[4], wk[4], wvf[4];
  {
    const float* r1 = W1 + (wv*16 + l15)*128 + q4*8;
    const float* r2 = W2 + (wv*16 + l15)*128 + q4*8;
    const float* r3 = W3 + (wv*16 + l15)*128 + q4*8;
    #pragma unroll
    for (int k0 = 0; k0 < 4; ++k0) {
      #pragma unroll
      for (int j = 0; j < 8; ++j) {
        wq[k0][j]  = (f16)(r1[k0*32 + j] * LOG2E);
        wk[k0][j]  = (f16)(r2[k0*32 + j]);
        wvf[k0][j] = (f16)(r3[k0*32 + j]);
      }
    }
  }
  __syncthreads();

  #pragma unroll
  for (int mt = 0; mt < 4; ++mt) {
    float4_t cq = {0.f,0.f,0.f,0.f}, ck = {0.f,0.f,0.f,0.f}, cv = {0.f,0.f,0.f,0.f};
    #pragma unroll
    for (int k0 = 0; k0 < 4; ++k0) {
      half8_t xa = *(half8_t*)&xs[(mt*16 + l15)*136 + k0*32 + q4*8];
      cq = __builtin_amdgcn_mfma_f32_16x16x32_f16(wq[k0],  xa, cq, 0, 0, 0); // D[cout][px]
      ck = __builtin_amdgcn_mfma_f32_16x16x32_f16(wk[k0],  xa, ck, 0, 0, 0); // D[cout][px]
      cv = __builtin_amdgcn_mfma_f32_16x16x32_f16(xa, wvf[k0], cv, 0, 0, 0); // D[px][cout]
    }
    int pxq = pxt + mt*16 + l15;                 // Q/K: col = px
    int g   = wv*2 + (q4 >> 1);                  // cout = wv*16 + q4*4 + r
    half4_t hq = {(f16)cq[0], (f16)cq[1], (f16)cq[2], (f16)cq[3]};
    half4_t hk = {(f16)ck[0], (f16)ck[1], (f16)ck[2], (f16)ck[3]};
    *(half4_t*)&Qi[((size_t)g * PLANE + pxq) * 8 + (q4 & 1)*4] = hq;
    *(half4_t*)&Ki[((size_t)g * PLANE + pxq) * 8 + (q4 & 1)*4] = hk;
    half4_t hv = {(f16)cv[0], (f16)cv[1], (f16)cv[2], (f16)cv[3]};
    *(half4_t*)&V2[(size_t)(wv*16 + l15) * PLANE + pxt + mt*16 + q4*4] = hv;
  }
}

// ============ Kernel 2: fused flash local attention, row-paired + K/V prefetch ============
__global__ __launch_bounds__(256, 3) void attn_fused_k(
    const f16* __restrict__ Qi, const f16* __restrict__ Ki,
    const f16* __restrict__ V2, float* __restrict__ out)
{
  __shared__ __align__(16) f16 plds[4][2][16 * 40];   // 10.2 KB

  int tid = threadIdx.x, lane = tid & 63, wv = tid >> 6;
  int l15 = lane & 15, q4 = lane >> 4;
  int b = blockIdx.x;
  int n = b & 7;                                  // XCD swizzle
  int r = b >> 3;                                 // 0..127
  int p = r & 63, hseg = r >> 6;
  int h0 = (p >> 1)*4 + (p & 1);                  // rows h0, h0+2 cover all h
  int h2 = h0 + 2;
  int seg = (hseg*4 + wv) * 16;
  int nb = n << 14;

  f16* P0 = &plds[wv][0][0];
  f16* P1 = &plds[wv][1][0];

  half8_t aq0[2], aq1[2];
  {
    int px0 = nb + (h0 << 7) + seg + l15;
    aq0[0] = *(const half8_t*)&Qi[((size_t)(q4    ) * PLANE + px0) * 8];
    aq0[1] = *(const half8_t*)&Qi[((size_t)(q4 + 4) * PLANE + px0) * 8];
    int px1 = px0 + 256;
    aq1[0] = *(const half8_t*)&Qi[((size_t)(q4    ) * PLANE + px1) * 8];
    aq1[1] = *(const half8_t*)&Qi[((size_t)(q4 + 4) * PLANE + px1) * 8];
  }

  unsigned vbits = 0;
  #pragma unroll
  for (int jt = 0; jt < 2; ++jt)
    #pragma unroll
    for (int rr = 0; rr < 4; ++rr) {
      int jw = seg - 8 + jt*16 + q4*4 + rr;
      int iw = seg + l15;
      int d  = jw - iw;
      bool val = (((d & 1) == 0) & (d >= -8) & (d <= 8) & ((unsigned)jw < 128u));
      vbits |= ((unsigned)val) << (jt*4 + rr);
    }

  float m0 = -1e30f, s0 = 0.f, m1 = -1e30f, s1 = 0.f;
  float4_t o0[4], o1[4];
  #pragma unroll
  for (int ct = 0; ct < 4; ++ct) {
    o0[ct] = (float4_t){0.f,0.f,0.f,0.f};
    o1[ct] = (float4_t){0.f,0.f,0.f,0.f};
  }

  auto row_body = [&](const half8_t* aq, float& m, float& l,
                      float4_t* o, f16* P, const half8_t (&bk)[2][2],
                      const half8_t (&bv)[4]) {
    float4_t st0 = (float4_t){0.f,0.f,0.f,0.f};
    float4_t st1 = (float4_t){0.f,0.f,0.f,0.f};
    st0 = __builtin_amdgcn_mfma_f32_16x16x32_f16(bk[0][0], aq[0], st0, 0, 0, 0);
    st0 = __builtin_amdgcn_mfma_f32_16x16x32_f16(bk[0][1], aq[1], st0, 0, 0, 0);
    st1 = __builtin_amdgcn_mfma_f32_16x16x32_f16(bk[1][0], aq[0], st1, 0, 0, 0);
    st1 = __builtin_amdgcn_mfma_f32_16x16x32_f16(bk[1][1], aq[1], st1, 0, 0, 0);
    #pragma unroll
    for (int rr = 0; rr < 4; ++rr) {
      st0[rr] = ((vbits >> rr)       & 1u) ? st0[rr] : -1e30f;
      st1[rr] = ((vbits >> (4 + rr)) & 1u) ? st1[rr] : -1e30f;
    }
    float v = fmaxf(fmaxf(fmaxf(st0[0], st0[1]), fmaxf(st0[2], st0[3])),
                    fmaxf(fmaxf(st1[0], st1[1]), fmaxf(st1[2], st1[3])));
    v = fmaxf(v, __shfl_xor(v, 16, 64));
    v = fmaxf(v, __shfl_xor(v, 32, 64));
    float mn = fmaxf(m, v);
    float al = exp2f(m - mn);
    m = mn;
    #pragma unroll
    for (int rr = 0; rr < 4; ++rr) {
      st0[rr] = exp2f(st0[rr] - mn);
      st1[rr] = exp2f(st1[rr] - mn);
    }
    float rs = (st0[0] + st0[1]) + (st0[2] + st0[3])
             + (st1[0] + st1[1]) + (st1[2] + st1[3]);
    rs += __shfl_xor(rs, 16, 64);
    rs += __shfl_xor(rs, 32, 64);
    l = l * al + rs;
    float4_t alv;
    #pragma unroll
    for (int rr = 0; rr < 4; ++rr) alv[rr] = __shfl(al, q4*4 + rr, 64);
    #pragma unroll
    for (int ct = 0; ct < 4; ++ct)
      #pragma unroll
      for (int rr = 0; rr < 4; ++rr) o[ct][rr] *= alv[rr];
    half4_t p0 = {(f16)st0[0], (f16)st0[1], (f16)st0[2], (f16)st0[3]};
    half4_t p1 = {(f16)st1[0], (f16)st1[1], (f16)st1[2], (f16)st1[3]};
    *(half4_t*)&P[l15*40      + q4*4] = p0;
    *(half4_t*)&P[l15*40 + 16 + q4*4] = p1;
    half8_t ap = *(half8_t*)&P[l15*40 + q4*8];
    #pragma unroll
    for (int ct = 0; ct < 4; ++ct)
      o[ct] = __builtin_amdgcn_mfma_f32_16x16x32_f16(ap, bv[ct], o[ct], 0, 0, 0);
  };

  auto loadKV = [&](int hs, half8_t (&bk)[2][2], half8_t (&bv)[4]) {
    int jbase = nb + (hs << 7) + seg - 8;        // mem-safe: +-128B stays in ws (guard)
    #pragma unroll
    for (int jt = 0; jt < 2; ++jt) {
      int pxj = jbase + jt*16 + l15;
      bk[jt][0] = *(const half8_t*)&Ki[((size_t)(q4    ) * PLANE + pxj) * 8];
      bk[jt][1] = *(const half8_t*)&Ki[((size_t)(q4 + 4) * PLANE + pxj) * 8];
    }
    #pragma unroll
    for (int ct = 0; ct < 4; ++ct)
      bv[ct] = *(const half8_t*)&V2[(size_t)(ct*16 + l15) * PLANE + jbase + q4*8];
  };

  auto process = [&](int hs, const half8_t (&bk)[2][2], const half8_t (&bv)[4]) {
    if (hs <= h0 + 8) row_body(aq0, m0, s0, o0, P0, bk, bv);
    if (hs >= h2 - 8) row_body(aq1, m1, s1, o1, P1, bk, bv);
  };

  int hs_lo = h0 - 8;  if (hs_lo < 0)   hs_lo = h0 & 1;
  int hs_hi = h0 + 10; if (hs_hi > 127) hs_hi = 126 + (h0 & 1);

  half8_t bkA[2][2], bvA[4], bkB[2][2], bvB[4];
  loadKV(hs_lo, bkA, bvA);
  int hs = hs_lo;
  while (true) {
    if (hs + 2 <= hs_hi) loadKV(hs + 2, bkB, bvB);
    process(hs, bkA, bvA);
    hs += 2; if (hs > hs_hi) break;
    if (hs + 2 <= hs_hi) loadKV(hs + 2, bkA, bvA);
    process(hs, bkB, bvB);
    hs += 2; if (hs > hs_hi) break;
  }

  int iw = seg + l15;
  int wlo = iw - 8; if (wlo < 0) wlo = 0;
  int whi = iw + 8; if (whi > 127) whi = 127;
  int vw = ((whi - wlo) >> 1) + 1;
  #pragma unroll
  for (int row = 0; row < 2; ++row) {
    int hr = row ? h2 : h0;
    int hlo = hr - 8; if (hlo < 0) hlo = 0;
    int hhi = hr + 8; if (hhi > 127) hhi = 127;
    int vh = ((hhi - hlo) >> 1) + 1;
    float cnt = (float)(81 - vh * vw);
    float m = row ? m1 : m0, l = row ? s1 : s0;
    float mn = fmaxf(m, 0.f);
    float em = exp2f(m - mn);
    float sc = em / (l * em + cnt * exp2f(-mn));
    float4_t scv;
    #pragma unroll
    for (int rr = 0; rr < 4; ++rr) scv[rr] = __shfl(sc, q4*4 + rr, 64);
    const float4_t* o = row ? o1 : o0;
    #pragma unroll
    for (int ct = 0; ct < 4; ++ct) {
      size_t ob = ((size_t)(n*COUT + ct*16 + l15) << 14) + (hr << 7) + seg + q4*4;
      float4_t stv;
      #pragma unroll
      for (int rr = 0; rr < 4; ++rr) stv[rr] = o[ct][rr] * scv[rr];
      *(float4_t*)&out[ob] = stv;
    }
  }
}

// ---------------- launcher ----------------
extern "C" void kernel_launch(void* const* d_in, const int* in_sizes, int n_in,
                              void* d_out, int out_size, void* d_ws, size_t ws_size,
                              hipStream_t stream)
{
  const float* x  = (const float*)d_in[0];
  const float* W1 = (const float*)d_in[1];
  const float* W2 = (const float*)d_in[2];
  const float* W3 = (const float*)d_in[3];

  // ws: guard(4KB) | Qi | Ki | V2 (+tail slack in the 268MB ws). Edge reads overrun
  // +-128B -> stay inside ws, masked to zero weight before use.
  f16* Qi = (f16*)d_ws + 2048;                       // [8][PLANE][8] interleaved
  f16* Ki = Qi + (size_t)8 * PLANE * 8;              // [8][PLANE][8]
  f16* V2 = Ki + (size_t)8 * PLANE * 8;              // [64][PLANE] planar

  float* outp = (float*)d_out;

  conv_mfma_k <<<NPIX/64, 256, 0, stream>>>(x, W1, W2, W3, Qi, Ki, V2);
  attn_fused_k<<<1024,    256, 0, stream>>>(Qi, Ki, V2, outp);
}

// Round 9
// 157.886 us; speedup vs baseline: 1.1146x; 1.1146x over previous
//
#include <hip/hip_runtime.h>
#include <hip/hip_bf16.h>
#include <cstdint>
#include <cstddef>

#define NB   8
#define CIN  128
#define COUT 64
#define NPIX 131072
#define PLANE NPIX
#define LOG2E 1.44269504088896340736f

typedef _Float16 f16;
typedef _Float16 half4_t __attribute__((ext_vector_type(4)));
typedef _Float16 half8_t __attribute__((ext_vector_type(8)));
typedef short    bs8    __attribute__((ext_vector_type(8)));  // bf16x8 frag (bit pattern)
typedef float    float4_t __attribute__((ext_vector_type(4)));
typedef unsigned int uint2_t __attribute__((ext_vector_type(2)));

// float -> bf16 bits, RNE
__device__ __forceinline__ unsigned short f2bf(float f){
  unsigned u = __float_as_uint(f);
  return (unsigned short)((u + 0x7fffu + ((u >> 16) & 1u)) >> 16);
}

// ============ Kernel 0: pack W1|W2|W3 -> f16 [192][128]; W1 pre-scaled by log2e ============
__global__ __launch_bounds__(256) void wsetup_k(
    const float* __restrict__ W1, const float* __restrict__ W2,
    const float* __restrict__ W3, f16* __restrict__ Wf)
{
  int idx = blockIdx.x * 256 + threadIdx.x;      // 0 .. 24575
  int mat = idx >> 13;
  int rem = idx & 8191;
  const float* src = (mat == 0 ? W1 : (mat == 1 ? W2 : W3));
  float v = src[rem];
  if (mat == 0) v *= LOG2E;                      // logits in base-2 -> exp2 in attn
  Wf[idx] = (f16)v;
}

// ============ Kernel 1: 1x1 convs, W-stationary MFMA (R7 structure; V -> bf16) ============
// Block 256 = 4 waves, 64-px tile. Wave wv owns Q/K/V 16-cout strips {wv, wv+4, wv+8};
// 12 W-frags (f16, L2-hot) preloaded once; 4 mt tiles with inlined epilogue.
__global__ __launch_bounds__(256, 4) void conv_mfma_k(
    const float* __restrict__ x, const f16* __restrict__ Wf,
    f16* __restrict__ Qi, f16* __restrict__ Ki, unsigned short* __restrict__ V2)
{
  __shared__ __align__(16) f16 xs[64 * 136];     // 17.4 KB

  int tid = threadIdx.x, lane = tid & 63, wv = tid >> 6;
  int pxt = blockIdx.x * 64;
  int n = pxt >> 14, hwt = pxt & 16383;

  // stage x[c][px] fp32 -> LDS [px][c] f16 (wave wv: channel strip wv*32)
  {
    const float* xp = x + ((size_t)(n * CIN + wv * 32) << 14) + hwt + lane;
    #pragma unroll
    for (int c0 = 0; c0 < 32; c0 += 8) {
      half8_t hh;
      #pragma unroll
      for (int j = 0; j < 8; ++j)
        hh[j] = (f16)xp[(size_t)(c0 + j) << 14];
      *(half8_t*)&xs[lane * 136 + wv * 32 + c0] = hh;
    }
  }
  __syncthreads();

  int l15 = lane & 15, q4 = lane >> 4;

  // preload W frags (reused across all mt)
  half8_t wq[4], wk[4], wvf[4];
  #pragma unroll
  for (int k0 = 0; k0 < 4; ++k0) {
    wq[k0]  = *(const half8_t*)&Wf[((wv     )*16 + l15)*128 + k0*32 + q4*8];
    wk[k0]  = *(const half8_t*)&Wf[((wv +  4)*16 + l15)*128 + k0*32 + q4*8];
    wvf[k0] = *(const half8_t*)&Wf[((wv +  8)*16 + l15)*128 + k0*32 + q4*8];
  }

  #pragma unroll
  for (int mt = 0; mt < 4; ++mt) {
    float4_t cq = {0.f,0.f,0.f,0.f}, ck = {0.f,0.f,0.f,0.f}, cv = {0.f,0.f,0.f,0.f};
    #pragma unroll
    for (int k0 = 0; k0 < 4; ++k0) {
      half8_t xa = *(half8_t*)&xs[(mt*16 + l15)*136 + k0*32 + q4*8];
      cq = __builtin_amdgcn_mfma_f32_16x16x32_f16(wq[k0],  xa, cq, 0, 0, 0); // D[cout][px]
      ck = __builtin_amdgcn_mfma_f32_16x16x32_f16(wk[k0],  xa, ck, 0, 0, 0); // D[cout][px]
      cv = __builtin_amdgcn_mfma_f32_16x16x32_f16(xa, wvf[k0], cv, 0, 0, 0); // D[px][cout]
    }
    int pxq = pxt + mt*16 + l15;                 // Q/K: col = px
    int g   = wv*2 + (q4 >> 1);                  // cout = wv*16 + q4*4 + r
    half4_t hq = {(f16)cq[0], (f16)cq[1], (f16)cq[2], (f16)cq[3]};
    half4_t hk = {(f16)ck[0], (f16)ck[1], (f16)ck[2], (f16)ck[3]};
    *(half4_t*)&Qi[((size_t)g * PLANE + pxq) * 8 + (q4 & 1)*4] = hq;
    *(half4_t*)&Ki[((size_t)g * PLANE + pxq) * 8 + (q4 & 1)*4] = hk;
    // V: planar bf16 [cout][px], row = px = q4*4+r (RNE pack)
    uint2_t pv;
    pv.x = (unsigned)f2bf(cv[0]) | ((unsigned)f2bf(cv[1]) << 16);
    pv.y = (unsigned)f2bf(cv[2]) | ((unsigned)f2bf(cv[3]) << 16);
    *(uint2_t*)&V2[(size_t)(wv*16 + l15) * PLANE + pxt + mt*16 + q4*4] = pv;
  }
}

// ============ Kernel 2: fused flash local attention, row-paired, NO-MAX softmax ============
// Block 512 = 8 waves; wave = 16-px segment of rows (h0, h0+2) (shared K/V rows).
// Logits bounded (|l_b2| <~ 60) -> exp2 without max subtraction is overflow-safe.
// Per hs: S^T = K.Q^T (f16 MFMA) -> mask -> exp2 -> per-lane partial sum + bf16 P
// (trunc pack) -> LDS -> O += P.V (bf16 MFMA). One normalize at the end:
// sc = 1/(s + cnt_oob) since each OOB offset contributes exp2(0) = 1.
__global__ __launch_bounds__(512, 4) void attn_fused_k(
    const f16* __restrict__ Qi, const f16* __restrict__ Ki,
    const unsigned short* __restrict__ V2, float* __restrict__ out)
{
  __shared__ __align__(16) unsigned short plds[8][2][16 * 40];   // 20.5 KB

  int tid = threadIdx.x, lane = tid & 63, wv = tid >> 6;
  int l15 = lane & 15, q4 = lane >> 4;
  int b = blockIdx.x;
  int n = b & 7;                                  // XCD swizzle: image n -> XCD n
  int p = b >> 3;                                 // 0..63
  int h0 = (p >> 1)*4 + (p & 1);                  // rows h0, h0+2 cover all h
  int h2 = h0 + 2;
  int seg = wv * 16;
  int nb = n << 14;

  unsigned short* P0 = &plds[wv][0][0];
  unsigned short* P1 = &plds[wv][1][0];

  // Q B-frags for both rows (n-dim = i = l15)
  half8_t aq0[2], aq1[2];
  {
    int px0 = nb + (h0 << 7) + seg + l15;
    aq0[0] = *(const half8_t*)&Qi[((size_t)(q4    ) * PLANE + px0) * 8];
    aq0[1] = *(const half8_t*)&Qi[((size_t)(q4 + 4) * PLANE + px0) * 8];
    int px1 = px0 + 256;
    aq1[0] = *(const half8_t*)&Qi[((size_t)(q4    ) * PLANE + px1) * 8];
    aq1[1] = *(const half8_t*)&Qi[((size_t)(q4 + 4) * PLANE + px1) * 8];
  }

  // dh-invariant validity: bit jt*4+r; lane j = seg-8+jt*16+q4*4+r, i = seg+l15
  unsigned vbits = 0;
  #pragma unroll
  for (int jt = 0; jt < 2; ++jt)
    #pragma unroll
    for (int rr = 0; rr < 4; ++rr) {
      int jw = seg - 8 + jt*16 + q4*4 + rr;
      int iw = seg + l15;
      int d  = jw - iw;
      bool val = (((d & 1) == 0) & (d >= -8) & (d <= 8) & ((unsigned)jw < 128u));
      vbits |= ((unsigned)val) << (jt*4 + rr);
    }

  float s0 = 0.f, s1 = 0.f;                       // per-lane partial denominators
  float4_t o0[4], o1[4];
  #pragma unroll
  for (int ct = 0; ct < 4; ++ct) {
    o0[ct] = (float4_t){0.f,0.f,0.f,0.f};
    o1[ct] = (float4_t){0.f,0.f,0.f,0.f};
  }

  auto row_body = [&](const half8_t* aq, float& s_part,
                      float4_t* o, unsigned short* P,
                      const half8_t (&bk)[2][2], const bs8 (&bv)[4]) {
    float4_t st0 = (float4_t){0.f,0.f,0.f,0.f};
    float4_t st1 = (float4_t){0.f,0.f,0.f,0.f};
    st0 = __builtin_amdgcn_mfma_f32_16x16x32_f16(bk[0][0], aq[0], st0, 0, 0, 0);
    st0 = __builtin_amdgcn_mfma_f32_16x16x32_f16(bk[0][1], aq[1], st0, 0, 0, 0);
    st1 = __builtin_amdgcn_mfma_f32_16x16x32_f16(bk[1][0], aq[0], st1, 0, 0, 0);
    st1 = __builtin_amdgcn_mfma_f32_16x16x32_f16(bk[1][1], aq[1], st1, 0, 0, 0);
    // mask -> exp2 (masked lanes: exp2(-1e30) = 0)
    #pragma unroll
    for (int rr = 0; rr < 4; ++rr) {
      st0[rr] = exp2f(((vbits >> rr)       & 1u) ? st0[rr] : -1e30f);
      st1[rr] = exp2f(((vbits >> (4 + rr)) & 1u) ? st1[rr] : -1e30f);
    }
    s_part += (st0[0] + st0[1]) + (st0[2] + st0[3])
            + (st1[0] + st1[1]) + (st1[2] + st1[3]);
    // P -> bf16 trunc pack (bias cancels in num/den ratio), 2x b64 LDS writes
    uint2_t pk0, pk1;
    pk0.x = (__float_as_uint(st0[1]) & 0xffff0000u) | (__float_as_uint(st0[0]) >> 16);
    pk0.y = (__float_as_uint(st0[3]) & 0xffff0000u) | (__float_as_uint(st0[2]) >> 16);
    pk1.x = (__float_as_uint(st1[1]) & 0xffff0000u) | (__float_as_uint(st1[0]) >> 16);
    pk1.y = (__float_as_uint(st1[3]) & 0xffff0000u) | (__float_as_uint(st1[2]) >> 16);
    *(uint2_t*)&P[l15*40      + q4*4] = pk0;
    *(uint2_t*)&P[l15*40 + 16 + q4*4] = pk1;
    bs8 ap = *(bs8*)&P[l15*40 + q4*8];            // A-layout read (K=32 exact)
    #pragma unroll
    for (int ct = 0; ct < 4; ++ct)
      o[ct] = __builtin_amdgcn_mfma_f32_16x16x32_bf16(ap, bv[ct], o[ct], 0, 0, 0);
  };

  for (int hs = h0 - 8; hs <= h0 + 10; hs += 2) {
    if (hs < 0 || hs > 127) continue;              // wave-uniform
    int jbase = nb + (hs << 7) + seg - 8;          // +-128B overrun stays in ws, masked

    half8_t bk[2][2];
    #pragma unroll
    for (int jt = 0; jt < 2; ++jt) {
      int pxj = jbase + jt*16 + l15;
      bk[jt][0] = *(const half8_t*)&Ki[((size_t)(q4    ) * PLANE + pxj) * 8];
      bk[jt][1] = *(const half8_t*)&Ki[((size_t)(q4 + 4) * PLANE + pxj) * 8];
    }
    bs8 bv[4];
    #pragma unroll
    for (int ct = 0; ct < 4; ++ct)
      bv[ct] = *(const bs8*)&V2[(size_t)(ct*16 + l15) * PLANE + jbase + q4*8];

    if (hs <= h0 + 8) row_body(aq0, s0, o0, P0, bk, bv);
    if (hs >= h2 - 8) row_body(aq1, s1, o1, P1, bk, bv);
  }

  // epilogue: reduce s over q4, add OOB count, normalize, float4 store
  int iw = seg + l15;
  int wlo = iw - 8; if (wlo < 0) wlo = 0;
  int whi = iw + 8; if (whi > 127) whi = 127;
  int vw = ((whi - wlo) >> 1) + 1;
  #pragma unroll
  for (int row = 0; row < 2; ++row) {
    int hr = row ? h2 : h0;
    int hlo = hr - 8; if (hlo < 0) hlo = 0;
    int hhi = hr + 8; if (hhi > 127) hhi = 127;
    int vh = ((hhi - hlo) >> 1) + 1;
    float cnt = (float)(81 - vh * vw);
    float srow = row ? s1 : s0;
    srow += __shfl_xor(srow, 16, 64);
    srow += __shfl_xor(srow, 32, 64);              // row-sum for i = l15
    float sc = 1.f / (srow + cnt);
    float4_t scv;
    #pragma unroll
    for (int rr = 0; rr < 4; ++rr) scv[rr] = __shfl(sc, q4*4 + rr, 64);
    const float4_t* o = row ? o1 : o0;
    #pragma unroll
    for (int ct = 0; ct < 4; ++ct) {
      size_t ob = ((size_t)(n*COUT + ct*16 + l15) << 14) + (hr << 7) + seg + q4*4;
      float4_t stv;
      #pragma unroll
      for (int rr = 0; rr < 4; ++rr) stv[rr] = o[ct][rr] * scv[rr];
      *(float4_t*)&out[ob] = stv;
    }
  }
}

// ---------------- launcher ----------------
extern "C" void kernel_launch(void* const* d_in, const int* in_sizes, int n_in,
                              void* d_out, int out_size, void* d_ws, size_t ws_size,
                              hipStream_t stream)
{
  const float* x  = (const float*)d_in[0];
  const float* W1 = (const float*)d_in[1];
  const float* W2 = (const float*)d_in[2];
  const float* W3 = (const float*)d_in[3];

  // ws: Wf | Qi | Ki | V2 (~42 MB of 268 MB; +-128B edge overruns stay inside ws,
  // masked to zero weight before use)
  f16* Wf = (f16*)d_ws;                              // [192][128] f16
  f16* Qi = Wf + (size_t)192 * 128;                  // [8][PLANE][8] f16 interleaved
  f16* Ki = Qi + (size_t)8 * PLANE * 8;              // [8][PLANE][8] f16
  unsigned short* V2 = (unsigned short*)(Ki + (size_t)8 * PLANE * 8); // [64][PLANE] bf16

  float* outp = (float*)d_out;

  wsetup_k    <<<96,       256, 0, stream>>>(W1, W2, W3, Wf);
  conv_mfma_k <<<NPIX/64,  256, 0, stream>>>(x, Wf, Qi, Ki, V2);
  attn_fused_k<<<NB*128/2, 512, 0, stream>>>(Qi, Ki, V2, outp);
}